// Round 4
// baseline (201.093 us; speedup 1.0000x reference)
//
#include <hip/hip_runtime.h>

// SpatialLinearAttention on MI355X — round 4: occupancy + sync-chain restructure.
// k_wconv (Wqkv->bf16)
// k_fqkv  (384x64 tile, 2 syncs, in-reg q-softmax, per-block ctx/sumexp partials)
// k_mbuild (reduce partials + M = Wout.blockdiag(ctx^T)*SCALE/n/sumexp -> bf16)
// k_out   (MFMA M @ q_sm + bout, direct stores, 1 sync, 32KB LDS)

constexpr float kSCALE = 0.17677669529663687f; // 32^-0.5

typedef __attribute__((ext_vector_type(8))) short short8;   // 8 bf16 (4 VGPRs)
typedef __attribute__((ext_vector_type(4))) float f32x4;    // MFMA acc

__device__ __forceinline__ float bfu2f(unsigned int u) {
  union { unsigned int i; float f; } c; c.i = u << 16; return c.f;
}
__device__ __forceinline__ unsigned short f2bf(float f) {
  union { float f; unsigned int i; } c; c.f = f;
  unsigned int r = c.i + 0x7fffu + ((c.i >> 16) & 1u);  // RNE
  return (unsigned short)(r >> 16);
}
__device__ __forceinline__ void pack8(const float* v, unsigned short* dst16) {
  union { unsigned short u[8]; uint4 q; } t;
  #pragma unroll
  for (int i = 0; i < 8; ++i) t.u[i] = f2bf(v[i]);
  *(uint4*)dst16 = t.q;
}

// ---------------------------------------------------------------- K0: W -> bf16
__global__ __launch_bounds__(256) void k_wconv(const float* __restrict__ W,
                                               unsigned short* __restrict__ Wbf) {
  const int i = (blockIdx.x * 256 + threadIdx.x) * 4;   // 49152 elems total
  const float4 v = *(const float4*)&W[i];
  union { unsigned short u[4]; uint2 q; } t;
  t.u[0] = f2bf(v.x); t.u[1] = f2bf(v.y); t.u[2] = f2bf(v.z); t.u[3] = f2bf(v.w);
  *(uint2*)&Wbf[i] = t.q;
}

// ---------------------------------------------------------------- K1: fused qkv
// grid (64 ntiles, 32 frames), 512 thr (8 waves: 4 o-groups x 2 n-groups; wave tile 96x32).
__global__ __launch_bounds__(512, 4) void k_fqkv(const float* __restrict__ x,
                                                 const unsigned short* __restrict__ Wbf,
                                                 unsigned short* __restrict__ qsm,
                                                 float* __restrict__ ctxp,
                                                 float* __restrict__ sexp) {
  __shared__ __align__(16) unsigned short R0[64 * 128];   // x-tile [n][c^]
  __shared__ __align__(16) unsigned short EK[128 * 64];   // exp(k) [d][n^]
  __shared__ __align__(16) unsigned short VV[128 * 64];   // v      [e][n^]
  const int ntile = blockIdx.x, fr = blockIdx.y;
  const int bb = fr >> 4, ff = fr & 15;
  const int tid = threadIdx.x;
  const float* xfr = x + ((size_t)bb * 2048 + ff) * 4096;   // [c][n], c-stride 65536 f32

  // ---- stage x: [64 n][128 c] bf16, strided coalesced dword gathers
  {
    const int nn = tid & 63, cg = tid >> 6;                 // 8 groups of 16 c
    const int ng = ntile * 64 + nn;
    #pragma unroll
    for (int p = 0; p < 2; ++p) {
      const int c8 = cg * 2 + p;
      float v[8];
      #pragma unroll
      for (int j = 0; j < 8; ++j) v[j] = xfr[(size_t)(c8 * 8 + j) * 65536 + ng];
      pack8(v, &R0[nn * 128 + ((c8 * 8) ^ ((nn & 7) << 3))]);
    }
  }
  __syncthreads();

  const int l = tid & 63, w = tid >> 6;
  const int wo = (w >> 1) * 96, wn = (w & 1) * 32;
  const int lr = l & 15, lg = l >> 4;
  f32x4 acc[6][2];
  #pragma unroll
  for (int i = 0; i < 6; ++i) { acc[i][0] = 0.f; acc[i][1] = 0.f; }

  // ---- GEMM: A fragments straight from L2-resident bf16 W; B from LDS
  #pragma unroll
  for (int ks = 0; ks < 4; ++ks) {
    const int k0 = ks * 32 + lg * 8;
    short8 a[6], b[2];
    #pragma unroll
    for (int i = 0; i < 6; ++i) a[i] = *(const short8*)&Wbf[(size_t)(wo + 16 * i + lr) * 128 + k0];
    #pragma unroll
    for (int j = 0; j < 2; ++j) {
      const int n = wn + 16 * j + lr;
      b[j] = *(const short8*)&R0[n * 128 + (k0 ^ ((n & 7) << 3))];
    }
    #pragma unroll
    for (int i = 0; i < 6; ++i)
      #pragma unroll
      for (int j = 0; j < 2; ++j)
        acc[i][j] = __builtin_amdgcn_mfma_f32_16x16x32_bf16(a[i], b[j], acc[i][j], 0, 0, 0);
  }

  // ---- epilogue: k -> exp -> EK; v -> VV (disjoint buffers, no sync needed yet)
  #pragma unroll
  for (int i = 0; i < 6; ++i) {
    const int grow = wo + 16 * i;
    if (grow >= 128 && grow < 256) {
      #pragma unroll
      for (int j = 0; j < 2; ++j) {
        const int n = wn + 16 * j + lr;
        #pragma unroll
        for (int r = 0; r < 4; ++r) {
          const int dd = grow - 128 + 4 * lg + r;
          EK[dd * 64 + (n ^ ((dd & 7) << 3))] = f2bf(__expf(acc[i][j][r]));
        }
      }
    } else if (grow >= 256) {
      #pragma unroll
      for (int j = 0; j < 2; ++j) {
        const int n = wn + 16 * j + lr;
        #pragma unroll
        for (int r = 0; r < 4; ++r) {
          const int e = grow - 256 + 4 * lg + r;
          VV[e * 64 + (n ^ ((e & 7) << 3))] = f2bf(acc[i][j][r]);
        }
      }
    }
  }
  // ---- q softmax fully in-register (head = frag pair), direct global store
  #pragma unroll
  for (int i0 = 0; i0 < 6; i0 += 2) {
    const int grow0 = wo + 16 * i0;
    if (grow0 < 128) {
      const int h = grow0 >> 5;
      #pragma unroll
      for (int j = 0; j < 2; ++j) {
        const int n = wn + 16 * j + lr;
        float v0[4], v1[4];
        float m = -1e30f;
        #pragma unroll
        for (int r = 0; r < 4; ++r) {
          v0[r] = acc[i0][j][r]; v1[r] = acc[i0 + 1][j][r];
          m = fmaxf(m, fmaxf(v0[r], v1[r]));
        }
        m = fmaxf(m, __shfl_xor(m, 16));
        m = fmaxf(m, __shfl_xor(m, 32));
        float s = 0.f;
        #pragma unroll
        for (int r = 0; r < 4; ++r) {
          v0[r] = __expf(v0[r] - m); v1[r] = __expf(v1[r] - m);
          s += v0[r] + v1[r];
        }
        s += __shfl_xor(s, 16);
        s += __shfl_xor(s, 32);
        const float inv = 1.f / s;
        union { unsigned short u[4]; uint2 q; } t0, t1;
        #pragma unroll
        for (int r = 0; r < 4; ++r) { t0.u[r] = f2bf(v0[r] * inv); t1.u[r] = f2bf(v1[r] * inv); }
        unsigned short* qb = qsm + ((size_t)fr * 4096 + ntile * 64 + n) * 128 + h * 32 + 4 * lg;
        *(uint2*)&qb[0]  = t0.q;
        *(uint2*)&qb[16] = t1.q;
      }
    }
  }
  __syncthreads();

  // ---- waves 0-3: per-head ctx partial via MFMA; waves 4-7: sumexp partial
  const int bp = fr * 64 + ntile;
  if (w < 4) {
    const int h = w;
    f32x4 c2[2][2];
    c2[0][0] = 0.f; c2[0][1] = 0.f; c2[1][0] = 0.f; c2[1][1] = 0.f;
    #pragma unroll
    for (int ks = 0; ks < 2; ++ks) {
      const int k0 = ks * 32 + lg * 8;
      short8 a2[2], b2[2];
      #pragma unroll
      for (int i2 = 0; i2 < 2; ++i2) {
        const int row = h * 32 + 16 * i2 + lr;
        a2[i2] = *(const short8*)&EK[row * 64 + (k0 ^ ((row & 7) << 3))];
      }
      #pragma unroll
      for (int j2 = 0; j2 < 2; ++j2) {
        const int row = h * 32 + 16 * j2 + lr;
        b2[j2] = *(const short8*)&VV[row * 64 + (k0 ^ ((row & 7) << 3))];
      }
      #pragma unroll
      for (int i2 = 0; i2 < 2; ++i2)
        #pragma unroll
        for (int j2 = 0; j2 < 2; ++j2)
          c2[i2][j2] = __builtin_amdgcn_mfma_f32_16x16x32_bf16(a2[i2], b2[j2], c2[i2][j2], 0, 0, 0);
    }
    float* cp = ctxp + ((size_t)bp * 4 + h) * 1024;
    #pragma unroll
    for (int i2 = 0; i2 < 2; ++i2)
      #pragma unroll
      for (int j2 = 0; j2 < 2; ++j2)
        #pragma unroll
        for (int r = 0; r < 4; ++r)
          cp[(16 * i2 + 4 * lg + r) * 32 + 16 * j2 + lr] = c2[i2][j2][r];
  } else {
    const int h = w - 4;
    const int rl = l & 31, half = l >> 5;
    const int row = h * 32 + rl;
    float s = 0.f;
    #pragma unroll
    for (int m = 0; m < 4; ++m) {
      const int ng = (half * 32 + m * 8) ^ ((row & 7) << 3);
      const uint4 u = *(const uint4*)&EK[row * 64 + ng];
      s += bfu2f(u.x & 0xffffu) + bfu2f(u.x >> 16) + bfu2f(u.y & 0xffffu) + bfu2f(u.y >> 16)
         + bfu2f(u.z & 0xffffu) + bfu2f(u.z >> 16) + bfu2f(u.w & 0xffffu) + bfu2f(u.w >> 16);
    }
    s += __shfl_xor(s, 32);
    if (half == 0) sexp[(size_t)bp * 128 + row] = s;
  }
}

// -------------------------------------------- K2: reduce partials + build M (bf16)
// grid (4 heads, 32 frames), 256 thr.
__global__ __launch_bounds__(256) void k_mbuild(const float* __restrict__ Wout,
                                                const float* __restrict__ ctxp,
                                                const float* __restrict__ sexp,
                                                unsigned short* __restrict__ Mbf) {
  __shared__ float Wo[128][33];   // Wout[o][h*32+e]
  __shared__ float cn[32][36];    // normalized ctx^T-ish [d][e]
  __shared__ float ses[32];
  const int h = blockIdx.x, fr = blockIdx.y, tid = threadIdx.x;

  // ctx partial sum: each thread owns 4 consecutive elems of this head's 32x32
  float4 c4 = make_float4(0.f, 0.f, 0.f, 0.f);
  {
    const float* base = ctxp + ((size_t)fr * 64) * 4096 + h * 1024 + tid * 4;
    #pragma unroll 8
    for (int p = 0; p < 64; ++p) {
      const float4 v = *(const float4*)&base[(size_t)p * 4096];
      c4.x += v.x; c4.y += v.y; c4.z += v.z; c4.w += v.w;
    }
  }
  // sumexp partial sum (threads 0-31)
  if (tid < 32) {
    float s = 0.f;
    const float* sb = sexp + ((size_t)fr * 64) * 128 + h * 32 + tid;
    #pragma unroll 8
    for (int p = 0; p < 64; ++p) s += sb[(size_t)p * 128];
    ses[tid] = s;
  }
  // stage Wout columns for this head
  {
    const int o = tid >> 1, e0 = (tid & 1) * 16;
    #pragma unroll
    for (int q = 0; q < 4; ++q) {
      const float4 v = *(const float4*)&Wout[o * 128 + h * 32 + e0 + 4 * q];
      Wo[o][e0 + 4 * q] = v.x; Wo[o][e0 + 4 * q + 1] = v.y;
      Wo[o][e0 + 4 * q + 2] = v.z; Wo[o][e0 + 4 * q + 3] = v.w;
    }
  }
  __syncthreads();
  {
    const int dd = tid >> 3, e0 = (tid & 7) * 4;
    const float sc = kSCALE / (4096.f * ses[dd]);
    cn[dd][e0] = c4.x * sc; cn[dd][e0 + 1] = c4.y * sc;
    cn[dd][e0 + 2] = c4.z * sc; cn[dd][e0 + 3] = c4.w * sc;
  }
  __syncthreads();
  // M[o][h*32+dc] = sum_e Wo[o][e] * cn[dc][e]
  {
    const int o = tid >> 1, dbase = (tid & 1) * 16;
    union { unsigned short u[16]; uint4 q[2]; } t;
    #pragma unroll
    for (int dq = 0; dq < 16; ++dq) {
      const int dc = dbase + dq;
      float s = 0.f;
      #pragma unroll
      for (int e = 0; e < 32; ++e) s = fmaf(Wo[o][e], cn[dc][e], s);
      t.u[dq] = f2bf(s);
    }
    unsigned short* mb = Mbf + (size_t)fr * 16384 + o * 128 + h * 32 + dbase;
    *(uint4*)&mb[0] = t.q[0];
    *(uint4*)&mb[8] = t.q[1];
  }
}

// ------------------------------------ K3: MFMA M @ q_sm + bout, direct stores, 1 sync
// grid (32 ntiles, 32 frames), 256 thr.
__global__ __launch_bounds__(256, 4) void k_out(const unsigned short* __restrict__ qsm,
                                                const unsigned short* __restrict__ Mbf,
                                                const float* __restrict__ bout,
                                                float* __restrict__ out) {
  __shared__ __align__(16) unsigned short Bp[128 * 128];   // q_sm tile [n][c^]
  const int ntile = blockIdx.x, fr = blockIdx.y;
  const int bb = fr >> 4, ff = fr & 15;
  const int tid = threadIdx.x;
  {
    const int c8 = (tid & 15) * 8;
    int n = tid >> 4;
    const unsigned short* qb = qsm + ((size_t)fr * 4096 + ntile * 128) * 128;
    #pragma unroll
    for (int p = 0; p < 8; ++p, n += 16) {
      const uint4 qv = *(const uint4*)&qb[n * 128 + c8];
      *(uint4*)&Bp[n * 128 + (c8 ^ ((n & 7) << 3))] = qv;
    }
  }
  __syncthreads();

  const int l = tid & 63, w = tid >> 6;
  const int wo = (w >> 1) * 64, wn = (w & 1) * 64;
  const int lr = l & 15, lg = l >> 4;
  f32x4 acc[4][4];
  #pragma unroll
  for (int i = 0; i < 4; ++i)
    #pragma unroll
    for (int j = 0; j < 4; ++j) acc[i][j] = 0.f;

  const unsigned short* Mf = Mbf + (size_t)fr * 16384;
  #pragma unroll
  for (int ks = 0; ks < 4; ++ks) {
    const int k0 = ks * 32 + lg * 8;
    short8 a[4], b[4];
    #pragma unroll
    for (int i = 0; i < 4; ++i) a[i] = *(const short8*)&Mf[(wo + 16 * i + lr) * 128 + k0];
    #pragma unroll
    for (int j = 0; j < 4; ++j) {
      const int n = wn + 16 * j + lr;
      b[j] = *(const short8*)&Bp[n * 128 + (k0 ^ ((n & 7) << 3))];
    }
    #pragma unroll
    for (int i = 0; i < 4; ++i)
      #pragma unroll
      for (int j = 0; j < 4; ++j)
        acc[i][j] = __builtin_amdgcn_mfma_f32_16x16x32_bf16(a[i], b[j], acc[i][j], 0, 0, 0);
  }

  // ---- direct stores: 16 lanes x 4B = 64B coalesced chunks, + bout from regs
  float* ofr = out + ((size_t)bb * 2048 + ff) * 4096;   // + o*65536 + n
  #pragma unroll
  for (int i = 0; i < 4; ++i) {
    const int o0 = wo + 16 * i + 4 * lg;
    const float4 bo = *(const float4*)&bout[o0];
    #pragma unroll
    for (int j = 0; j < 4; ++j) {
      const int n = ntile * 128 + wn + 16 * j + lr;
      ofr[(size_t)(o0 + 0) * 65536 + n] = acc[i][j][0] + bo.x;
      ofr[(size_t)(o0 + 1) * 65536 + n] = acc[i][j][1] + bo.y;
      ofr[(size_t)(o0 + 2) * 65536 + n] = acc[i][j][2] + bo.z;
      ofr[(size_t)(o0 + 3) * 65536 + n] = acc[i][j][3] + bo.w;
    }
  }
}

extern "C" void kernel_launch(void* const* d_in, const int* in_sizes, int n_in,
                              void* d_out, int out_size, void* d_ws, size_t ws_size,
                              hipStream_t stream) {
  const float* x    = (const float*)d_in[0];
  const float* Wqkv = (const float*)d_in[1];
  const float* Wout = (const float*)d_in[2];
  const float* bout = (const float*)d_in[3];
  float* out = (float*)d_out;

  char* ws = (char*)d_ws;
  // qsm bf16 [32][4096][128] | ctxp f32 [2048][4][32][32] | sexp f32 [2048][128]
  // | Mbf bf16 [32][128][128] | Wbf bf16 [384][128]
  unsigned short* qsm = (unsigned short*)ws;                 // 33,554,432 B
  float* ctxp  = (float*)(ws + 33554432u);                   // 33,554,432 B
  float* sexp  = (float*)(ws + 67108864u);                   //  1,048,576 B
  unsigned short* Mbf = (unsigned short*)(ws + 68157440u);   //  1,048,576 B
  unsigned short* Wbf = (unsigned short*)(ws + 69206016u);   //     98,304 B
  // total 69,304,320 B — no memset needed (no atomics; all buffers fully written)

  k_wconv<<<dim3(48), 256, 0, stream>>>(Wqkv, Wbf);
  k_fqkv<<<dim3(64, 32), 512, 0, stream>>>(x, Wbf, qsm, ctxp, sexp);
  k_mbuild<<<dim3(4, 32), 256, 0, stream>>>(Wout, ctxp, sexp, Mbf);
  k_out<<<dim3(32, 32), 256, 0, stream>>>(qsm, Mbf, bout, out);
}